// Round 1
// baseline (3060.392 us; speedup 1.0000x reference)
//
#include <hip/hip_runtime.h>
#include <hip/hip_bf16.h>
#include <stdint.h>

// Problem dims (fixed)
//  B=1024, D_in=1024, D_hid=1024, D_out=512, D_future=32
// Outputs (flat, in order): Act [1024*512], Act_bar [32*1024*512],
//                           hx2 [1024*1024], cx2 [1024*1024]

typedef unsigned short ushort_t;
typedef __attribute__((ext_vector_type(8))) short short8;   // 8 x bf16 (4 VGPRs)
typedef __attribute__((ext_vector_type(4))) float floatx4;  // 4 x fp32 acc

__device__ __forceinline__ unsigned short f2bf(float f) {
    unsigned int u = __float_as_uint(f);
    u += 0x7FFF + ((u >> 16) & 1);   // RNE
    return (unsigned short)(u >> 16);
}
__device__ __forceinline__ float sigm(float x) { return 1.f / (1.f + __expf(-x)); }

__device__ __forceinline__ void glds16(const ushort_t* g, const ushort_t* l) {
    __builtin_amdgcn_global_load_lds(
        (const __attribute__((address_space(1))) uint32_t*)g,
        (__attribute__((address_space(3))) uint32_t*)l, 16, 0, 0);
}

// C[m][n] = sum_k A[m][k] * Bw[n][k] + bias[n], optional relu,
// writes fp32 (Cf/ldcf) and/or bf16 (Cb/ldcb).
// A: bf16 row-major with leading dim lda; Bw: bf16 [N][K] row-major.
// Requires M%128==0, N%128==0, K%32==0. Grid: (N/128, M/128), block 256.
template <bool WF, bool WB, bool RELU>
__global__ __launch_bounds__(256)
void gemm_bt(const ushort_t* __restrict__ A, int lda,
             const ushort_t* __restrict__ Bw, int K,
             const float* __restrict__ bias,
             float* __restrict__ Cf, int ldcf,
             ushort_t* __restrict__ Cb, int ldcb) {
    __shared__ __align__(16) ushort_t As[128 * 32];
    __shared__ __align__(16) ushort_t Bs[128 * 32];
    const int t = threadIdx.x;
    const int l = t & 63;
    const int w = t >> 6;
    const int m0 = blockIdx.y << 7;
    const int n0 = blockIdx.x << 7;
    const int wm = (w >> 1) << 6;  // wave row offset in tile
    const int wn = (w & 1) << 6;   // wave col offset in tile
    const int lr = l & 15;
    const int lg = l >> 4;

    floatx4 acc[4][4] = {};

    // staging: thread t loads 8 bf16 from row (t>>2), cols (t&3)*8..+8
    const int srow = t >> 2;
    const int scol = (t & 3) << 3;
    const ushort_t* Ag0 = A + (size_t)(m0 + srow) * lda + scol;
    const ushort_t* Ag1 = Ag0 + (size_t)64 * lda;
    const ushort_t* Bg0 = Bw + (size_t)(n0 + srow) * K + scol;
    const ushort_t* Bg1 = Bg0 + (size_t)64 * K;
    const ushort_t* lA0 = &As[t * 8];
    const ushort_t* lA1 = &As[2048 + t * 8];
    const ushort_t* lB0 = &Bs[t * 8];
    const ushort_t* lB1 = &Bs[2048 + t * 8];

    for (int kk = 0; kk < K; kk += 32) {
        glds16(Ag0 + kk, lA0);
        glds16(Ag1 + kk, lA1);
        glds16(Bg0 + kk, lB0);
        glds16(Bg1 + kk, lB1);
        __syncthreads();  // compiler emits s_waitcnt vmcnt(0) before s_barrier

        short8 af[4], bfr[4];
#pragma unroll
        for (int i = 0; i < 4; i++)
            af[i] = *(const short8*)&As[(wm + i * 16 + lr) * 32 + lg * 8];
#pragma unroll
        for (int j = 0; j < 4; j++)
            bfr[j] = *(const short8*)&Bs[(wn + j * 16 + lr) * 32 + lg * 8];
#pragma unroll
        for (int i = 0; i < 4; i++)
#pragma unroll
            for (int j = 0; j < 4; j++)
                acc[i][j] = __builtin_amdgcn_mfma_f32_16x16x32_bf16(af[i], bfr[j], acc[i][j], 0, 0, 0);
        __syncthreads();
    }

#pragma unroll
    for (int i = 0; i < 4; i++) {
#pragma unroll
        for (int j = 0; j < 4; j++) {
            const int col = n0 + wn + j * 16 + lr;
            const float bv = bias[col];
#pragma unroll
            for (int r = 0; r < 4; r++) {
                const int row = m0 + wm + i * 16 + lg * 4 + r;
                float v = acc[i][j][r] + bv;
                if (RELU) v = fmaxf(v, 0.f);
                if (WF) Cf[(size_t)row * ldcf + col] = v;
                if (WB) Cb[(size_t)row * ldcb + col] = f2bf(v);
            }
        }
    }
}

// dst[n][k] bf16 <- concat(s1[n][0..K1), s2[n][0..K2)). grid ((K1+K2)/256, N)
__global__ void pack2_bf(ushort_t* __restrict__ dst, const float* __restrict__ s1, int K1,
                         const float* __restrict__ s2, int K2) {
    const int n = blockIdx.y;
    const int k = blockIdx.x * 256 + threadIdx.x;
    const int Kt = K1 + K2;
    float v = (k < K1) ? s1[(size_t)n * K1 + k] : s2[(size_t)n * K2 + (k - K1)];
    dst[(size_t)n * Kt + k] = f2bf(v);
}

__global__ void addvec(float* dst, const float* a, const float* b) {
    int i = blockIdx.x * 256 + threadIdx.x;
    dst[i] = a[i] + b[i];
}

// cd=cx, hsum=0, Acat r-columns (0..511) = 0. grid 4096x256 over 1M
__global__ void init_dec(const float* __restrict__ cx, float* __restrict__ cd,
                         float* __restrict__ hsum, ushort_t* __restrict__ Acat) {
    int idx = blockIdx.x * 256 + threadIdx.x;
    cd[idx] = cx[idx];
    hsum[idx] = 0.f;
    int b = idx >> 10, j = idx & 1023;
    if (j < 512) Acat[(size_t)b * 1536 + j] = 0;  // bf16 zero
}

// Acat2: cols 0..1023 = bf(x), cols 2048..3071 = bf(hx). grid 4096x256 over 1M
__global__ void init_sta(const float* __restrict__ x, const float* __restrict__ hx,
                         ushort_t* __restrict__ A2) {
    int idx = blockIdx.x * 256 + threadIdx.x;
    int b = idx >> 10, j = idx & 1023;
    A2[(size_t)b * 3072 + j] = f2bf(x[idx]);
    A2[(size_t)b * 3072 + 2048 + j] = f2bf(hx[idx]);
}

// Decoder LSTM pointwise. gates [B][4096] (i,f,g,o), cd in/out fp32,
// h -> Acat cols 512..1535 (bf16), hsum += h. grid 4096x256 over 1M
__global__ void lstm_dec_pw(const float* __restrict__ gates, float* __restrict__ cd,
                            ushort_t* __restrict__ Acat, float* __restrict__ hsum) {
    int idx = blockIdx.x * 256 + threadIdx.x;
    int b = idx >> 10, j = idx & 1023;
    const float* g = gates + ((size_t)b << 12);
    float ig = sigm(g[j]);
    float fg = sigm(g[1024 + j]);
    float gg = tanhf(g[2048 + j]);
    float og = sigm(g[3072 + j]);
    float c = fg * cd[idx] + ig * gg;
    float h = og * tanhf(c);
    cd[idx] = c;
    hsum[idx] += h;
    Acat[(size_t)b * 1536 + 512 + j] = f2bf(h);
}

__global__ void hbar_bf_k(const float* __restrict__ hsum, ushort_t* __restrict__ out) {
    int idx = blockIdx.x * 256 + threadIdx.x;
    out[idx] = f2bf(hsum[idx] * (1.f / 32.f));
}

// Static LSTM pointwise: h2,c2 fp32 to d_out, h2 bf16 for final GEMM.
__global__ void lstm_sta_pw(const float* __restrict__ gates, const float* __restrict__ cx,
                            float* __restrict__ oh, float* __restrict__ oc,
                            ushort_t* __restrict__ hbf) {
    int idx = blockIdx.x * 256 + threadIdx.x;
    int b = idx >> 10, j = idx & 1023;
    const float* g = gates + ((size_t)b << 12);
    float ig = sigm(g[j]);
    float fg = sigm(g[1024 + j]);
    float gg = tanhf(g[2048 + j]);
    float og = sigm(g[3072 + j]);
    float c = fg * cx[idx] + ig * gg;
    float h = og * tanhf(c);
    oc[idx] = c;
    oh[idx] = h;
    hbf[idx] = f2bf(h);
}

extern "C" void kernel_launch(void* const* d_in, const int* in_sizes, int n_in,
                              void* d_out, int out_size, void* d_ws, size_t ws_size,
                              hipStream_t stream) {
    const float* x        = (const float*)d_in[0];
    const float* hx       = (const float*)d_in[1];
    const float* cx       = (const float*)d_in[2];
    const float* W_ih_dec = (const float*)d_in[3];
    const float* W_hh_dec = (const float*)d_in[4];
    const float* b_ih_dec = (const float*)d_in[5];
    const float* b_hh_dec = (const float*)d_in[6];
    const float* W_r0     = (const float*)d_in[7];
    const float* b_r0     = (const float*)d_in[8];
    const float* W_rp     = (const float*)d_in[9];
    const float* b_rp     = (const float*)d_in[10];
    const float* W_rr     = (const float*)d_in[11];
    const float* b_rr     = (const float*)d_in[12];
    const float* W_s0     = (const float*)d_in[13];
    const float* b_s0     = (const float*)d_in[14];
    const float* W_ih_sta = (const float*)d_in[15];
    const float* W_hh_sta = (const float*)d_in[16];
    const float* b_ih_sta = (const float*)d_in[17];
    const float* b_hh_sta = (const float*)d_in[18];
    const float* W_sn     = (const float*)d_in[19];
    const float* b_sn     = (const float*)d_in[20];
    float* out = (float*)d_out;

    float* Act    = out;                          // [1024][512]
    float* ActBar = out + 524288;                 // [32][1024][512]
    float* Hx2    = out + 524288 + 16777216;      // [1024][1024]
    float* Cx2    = Hx2 + 1048576;                // [1024][1024]

    char* ws = (char*)d_ws;
    size_t off = 0;
    auto alloc = [&](size_t bytes) -> void* {
        void* p = ws + off;
        off += (bytes + 255) & ~(size_t)255;
        return p;
    };
    ushort_t* WcatD = (ushort_t*)alloc(4096ull * 1536 * 2);  // [4096][512|1024]
    ushort_t* Wr0b  = (ushort_t*)alloc(1024ull * 1024 * 2);
    ushort_t* Wrpb  = (ushort_t*)alloc(512ull * 1024 * 2);
    ushort_t* Wrrb  = (ushort_t*)alloc(512ull * 512 * 2);
    ushort_t* Ws0b  = (ushort_t*)alloc(1024ull * 1024 * 2);
    ushort_t* Wsnb  = (ushort_t*)alloc(512ull * 1024 * 2);
    ushort_t* WcatS = (ushort_t*)alloc(4096ull * 3072 * 2);  // [4096][2048|1024]
    float*    biasD = (float*)alloc(4096 * 4);
    float*    biasS = (float*)alloc(4096 * 4);
    float*    gates = (float*)alloc(1024ull * 4096 * 4);
    ushort_t* Acat  = (ushort_t*)alloc(1024ull * 1536 * 2);  // [r(512) | hd(1024)]
    ushort_t* Acat2 = (ushort_t*)alloc(1024ull * 3072 * 2);  // [x | xbar | hx]
    float*    cd    = (float*)alloc(1024ull * 1024 * 4);
    float*    hsum  = (float*)alloc(1024ull * 1024 * 4);
    ushort_t* pbuf  = (ushort_t*)alloc(1024ull * 512 * 2);
    ushort_t* hbarb = (ushort_t*)alloc(1024ull * 1024 * 2);
    ushort_t* hx2b  = (ushort_t*)alloc(1024ull * 1024 * 2);
    if (ws_size < off) return;  // insufficient workspace -> fail loudly in validation

    // ---- weight packing (runs every call; ~85 MB of traffic, ~20 us) ----
    pack2_bf<<<dim3(6, 4096), 256, 0, stream>>>(WcatD, W_ih_dec, 512, W_hh_dec, 1024);
    pack2_bf<<<dim3(4, 1024), 256, 0, stream>>>(Wr0b, W_r0, 1024, nullptr, 0);
    pack2_bf<<<dim3(4, 512), 256, 0, stream>>>(Wrpb, W_rp, 1024, nullptr, 0);
    pack2_bf<<<dim3(2, 512), 256, 0, stream>>>(Wrrb, W_rr, 512, nullptr, 0);
    pack2_bf<<<dim3(4, 1024), 256, 0, stream>>>(Ws0b, W_s0, 1024, nullptr, 0);
    pack2_bf<<<dim3(4, 512), 256, 0, stream>>>(Wsnb, W_sn, 1024, nullptr, 0);
    pack2_bf<<<dim3(12, 4096), 256, 0, stream>>>(WcatS, W_ih_sta, 2048, W_hh_sta, 1024);
    addvec<<<16, 256, 0, stream>>>(biasD, b_ih_dec, b_hh_dec);
    addvec<<<16, 256, 0, stream>>>(biasS, b_ih_sta, b_hh_sta);
    init_dec<<<4096, 256, 0, stream>>>(cx, cd, hsum, Acat);
    init_sta<<<4096, 256, 0, stream>>>(x, hx, Acat2);

    // hd0 = hx @ W_r0^T + b_r0  -> Acat cols 512..1535 (bf16)
    gemm_bt<false, true, false><<<dim3(8, 8), 256, 0, stream>>>(
        Acat2 + 2048, 3072, Wr0b, 1024, b_r0, nullptr, 0, Acat + 512, 1536);

    // ---- decoder loop ----
    for (int t = 0; t < 32; t++) {
        // gates = [r|hd] @ [W_ih|W_hh]^T + (b_ih+b_hh)
        gemm_bt<true, false, false><<<dim3(32, 8), 256, 0, stream>>>(
            Acat, 1536, WcatD, 1536, biasD, gates, 4096, nullptr, 0);
        lstm_dec_pw<<<4096, 256, 0, stream>>>(gates, cd, Acat, hsum);
        // p = hd @ W_rp^T + b_rp  -> Act_bar[t] (fp32) and pbuf (bf16)
        gemm_bt<true, true, false><<<dim3(4, 8), 256, 0, stream>>>(
            Acat + 512, 1536, Wrpb, 1024, b_rp,
            ActBar + (size_t)t * 524288, 512, pbuf, 512);
        // r = p @ W_rr^T + b_rr -> Acat cols 0..511 (skip on last step)
        if (t < 31)
            gemm_bt<false, true, false><<<dim3(4, 8), 256, 0, stream>>>(
                pbuf, 512, Wrrb, 512, b_rr, nullptr, 0, Acat, 1536);
    }

    // hbar = mean(fts_bar); xbar = relu(hbar @ W_s0^T + b_s0) -> Acat2 cols 1024..2047
    hbar_bf_k<<<4096, 256, 0, stream>>>(hsum, hbarb);
    gemm_bt<false, true, true><<<dim3(8, 8), 256, 0, stream>>>(
        hbarb, 1024, Ws0b, 1024, b_s0, nullptr, 0, Acat2 + 1024, 3072);

    // static LSTM: gates = [x|xbar|hx] @ [W_ih_sta|W_hh_sta]^T + biases
    gemm_bt<true, false, false><<<dim3(32, 8), 256, 0, stream>>>(
        Acat2, 3072, WcatS, 3072, biasS, gates, 4096, nullptr, 0);
    lstm_sta_pw<<<4096, 256, 0, stream>>>(gates, cx, Hx2, Cx2, hx2b);

    // Act = hx2 @ W_sn^T + b_sn
    gemm_bt<true, false, false><<<dim3(4, 8), 256, 0, stream>>>(
        hx2b, 1024, Wsnb, 1024, b_sn, Act, 512, nullptr, 0);

    (void)in_sizes; (void)n_in; (void)out_size;
}

// Round 2
// 2862.029 us; speedup vs baseline: 1.0693x; 1.0693x over previous
//
#include <hip/hip_runtime.h>
#include <hip/hip_bf16.h>
#include <stdint.h>

// Problem dims (fixed)
//  B=1024, D_in=1024, D_hid=1024, D_out=512, D_future=32
// Outputs (flat, in order): Act [1024*512], Act_bar [32*1024*512],
//                           hx2 [1024*1024], cx2 [1024*1024]

typedef unsigned short ushort_t;
typedef __attribute__((ext_vector_type(8))) short short8;   // 8 x bf16 (4 VGPRs)
typedef __attribute__((ext_vector_type(4))) float floatx4;  // 4 x fp32 acc

__device__ __forceinline__ unsigned short f2bf(float f) {
    unsigned int u = __float_as_uint(f);
    u += 0x7FFF + ((u >> 16) & 1);   // RNE
    return (unsigned short)(u >> 16);
}
__device__ __forceinline__ float sigm(float x) { return 1.f / (1.f + __expf(-x)); }

__device__ __forceinline__ void glds16(const ushort_t* g, const ushort_t* l) {
    __builtin_amdgcn_global_load_lds(
        (const __attribute__((address_space(1))) uint32_t*)g,
        (__attribute__((address_space(3))) uint32_t*)l, 16, 0, 0);
}

// C[m][n] = sum_k A[m][k] * Bw[n][k] (+ bias[n] if bias!=nullptr), optional relu.
// Split-K: blockIdx.z selects K-slice (A,Bw advanced by kzOff elems; Cf by czStride).
// LDS layout is XOR-swizzled at 16B-chunk granularity to kill ds_read_b128 bank
// conflicts: chunk (row, cc) lives at slot 4*row + ((cc + (row>>1))&3).
// Grid: (N/128, M/128, kz), block 256.
template <bool WF, bool WB, bool RELU>
__global__ __launch_bounds__(256)
void gemm_bt(const ushort_t* __restrict__ A, int lda,
             const ushort_t* __restrict__ Bw, int ldb,
             int Kloop, int kzOff,
             const float* __restrict__ bias,
             float* __restrict__ Cf, int ldcf, size_t czStride,
             ushort_t* __restrict__ Cb, int ldcb) {
    __shared__ __align__(16) ushort_t As[128 * 32];
    __shared__ __align__(16) ushort_t Bs[128 * 32];
    const int t = threadIdx.x;
    const int l = t & 63;
    const int w = t >> 6;
    const int m0 = blockIdx.y << 7;
    const int n0 = blockIdx.x << 7;
    const int kz = blockIdx.z;
    A  += (size_t)kz * kzOff;
    Bw += (size_t)kz * kzOff;
    if (WF) Cf += (size_t)kz * czStride;
    const int wm = (w >> 1) << 6;  // wave row offset in tile
    const int wn = (w & 1) << 6;   // wave col offset in tile
    const int lr = l & 15;
    const int lg = l >> 4;

    floatx4 acc[4][4] = {};

    // Swizzled staging: thread (w,l) stages chunk (srow, cc) into slot w*64+l
    // (call 0: rows 0..63 -> slots 0..255; call 1: rows 64..127 -> slots 256..511).
    // srow = w*16 + (l>>2); slot = 4*srow + (l&3); cc = ((l&3) - (srow>>1)) & 3.
    const int srow = (w << 4) + (l >> 2);
    const int cc = ((l & 3) - ((l >> 3) & 3)) & 3;   // (srow>>1)&3 == (l>>3)&3 here
    const int scol = cc << 3;
    const ushort_t* Ag0 = A + (size_t)(m0 + srow) * lda + scol;
    const ushort_t* Ag1 = A + (size_t)(m0 + 64 + srow) * lda + scol;
    const ushort_t* Bg0 = Bw + (size_t)(n0 + srow) * ldb + scol;
    const ushort_t* Bg1 = Bw + (size_t)(n0 + 64 + srow) * ldb + scol;
    const ushort_t* lA0 = &As[t * 8];
    const ushort_t* lA1 = &As[2048 + t * 8];
    const ushort_t* lB0 = &Bs[t * 8];
    const ushort_t* lB1 = &Bs[2048 + t * 8];

    // Fragment read offsets (constant across k): chunk (R, lg) at slot
    // 4R + ((lg + (R>>1)) & 3); offsets in elements = slot*8.
    int aoff[4], boff[4];
#pragma unroll
    for (int i = 0; i < 4; i++) {
        const int Ra = wm + i * 16 + lr;
        aoff[i] = ((Ra << 2) + ((lg + ((Ra >> 1) & 3)) & 3)) << 3;
        const int Rb = wn + i * 16 + lr;
        boff[i] = ((Rb << 2) + ((lg + ((Rb >> 1) & 3)) & 3)) << 3;
    }

    for (int kk = 0; kk < Kloop; kk += 32) {
        glds16(Ag0 + kk, lA0);
        glds16(Ag1 + kk, lA1);
        glds16(Bg0 + kk, lB0);
        glds16(Bg1 + kk, lB1);
        __syncthreads();  // compiler emits s_waitcnt vmcnt(0) before s_barrier

        short8 af[4], bfr[4];
#pragma unroll
        for (int i = 0; i < 4; i++) af[i] = *(const short8*)&As[aoff[i]];
#pragma unroll
        for (int j = 0; j < 4; j++) bfr[j] = *(const short8*)&Bs[boff[j]];
#pragma unroll
        for (int i = 0; i < 4; i++)
#pragma unroll
            for (int j = 0; j < 4; j++)
                acc[i][j] = __builtin_amdgcn_mfma_f32_16x16x32_bf16(af[i], bfr[j], acc[i][j], 0, 0, 0);
        __syncthreads();
    }

#pragma unroll
    for (int i = 0; i < 4; i++) {
#pragma unroll
        for (int j = 0; j < 4; j++) {
            const int col = n0 + wn + j * 16 + lr;
            const float bv = bias ? bias[col] : 0.f;
#pragma unroll
            for (int r = 0; r < 4; r++) {
                const int row = m0 + wm + i * 16 + lg * 4 + r;
                float v = acc[i][j][r] + bv;
                if (RELU) v = fmaxf(v, 0.f);
                if (WF) Cf[(size_t)row * ldcf + col] = v;
                if (WB) Cb[(size_t)row * ldcb + col] = f2bf(v);
            }
        }
    }
}

// dst[n][k] bf16 <- concat(s1[n][0..K1), s2[n][0..K2)). grid ((K1+K2)/256, N)
__global__ void pack2_bf(ushort_t* __restrict__ dst, const float* __restrict__ s1, int K1,
                         const float* __restrict__ s2, int K2) {
    const int n = blockIdx.y;
    const int k = blockIdx.x * 256 + threadIdx.x;
    const int Kt = K1 + K2;
    float v = (k < K1) ? s1[(size_t)n * K1 + k] : s2[(size_t)n * K2 + (k - K1)];
    dst[(size_t)n * Kt + k] = f2bf(v);
}

__global__ void addvec(float* dst, const float* a, const float* b) {
    int i = blockIdx.x * 256 + threadIdx.x;
    dst[i] = a[i] + b[i];
}

// cd=cx, hsum=0, Acat r-columns (0..511) = 0. grid 4096x256 over 1M
__global__ void init_dec(const float* __restrict__ cx, float* __restrict__ cd,
                         float* __restrict__ hsum, ushort_t* __restrict__ Acat) {
    int idx = blockIdx.x * 256 + threadIdx.x;
    cd[idx] = cx[idx];
    hsum[idx] = 0.f;
    int b = idx >> 10, j = idx & 1023;
    if (j < 512) Acat[(size_t)b * 1536 + j] = 0;  // bf16 zero
}

// Acat2: cols 0..1023 = bf(x), cols 2048..3071 = bf(hx). grid 4096x256 over 1M
__global__ void init_sta(const float* __restrict__ x, const float* __restrict__ hx,
                         ushort_t* __restrict__ A2) {
    int idx = blockIdx.x * 256 + threadIdx.x;
    int b = idx >> 10, j = idx & 1023;
    A2[(size_t)b * 3072 + j] = f2bf(x[idx]);
    A2[(size_t)b * 3072 + 2048 + j] = f2bf(hx[idx]);
}

// Decoder LSTM pointwise over split-K partials: gate = P0 + P1 + bias.
// cd in/out fp32, h -> Acat cols 512..1535 (bf16), hsum += h. grid 4096x256
__global__ void lstm_dec_pw(const float* __restrict__ P0, const float* __restrict__ P1,
                            const float* __restrict__ bias, float* __restrict__ cd,
                            ushort_t* __restrict__ Acat, float* __restrict__ hsum) {
    int idx = blockIdx.x * 256 + threadIdx.x;
    int b = idx >> 10, j = idx & 1023;
    const float* g0 = P0 + ((size_t)b << 12);
    const float* g1 = P1 + ((size_t)b << 12);
    float ig = sigm(g0[j] + g1[j] + bias[j]);
    float fg = sigm(g0[1024 + j] + g1[1024 + j] + bias[1024 + j]);
    float gg = tanhf(g0[2048 + j] + g1[2048 + j] + bias[2048 + j]);
    float og = sigm(g0[3072 + j] + g1[3072 + j] + bias[3072 + j]);
    float c = fg * cd[idx] + ig * gg;
    float h = og * tanhf(c);
    cd[idx] = c;
    hsum[idx] += h;
    Acat[(size_t)b * 1536 + 512 + j] = f2bf(h);
}

__global__ void hbar_bf_k(const float* __restrict__ hsum, ushort_t* __restrict__ out) {
    int idx = blockIdx.x * 256 + threadIdx.x;
    out[idx] = f2bf(hsum[idx] * (1.f / 32.f));
}

// Static LSTM pointwise over split-K partials: h2,c2 fp32 to d_out, h2 bf16.
__global__ void lstm_sta_pw(const float* __restrict__ P0, const float* __restrict__ P1,
                            const float* __restrict__ bias, const float* __restrict__ cx,
                            float* __restrict__ oh, float* __restrict__ oc,
                            ushort_t* __restrict__ hbf) {
    int idx = blockIdx.x * 256 + threadIdx.x;
    int b = idx >> 10, j = idx & 1023;
    const float* g0 = P0 + ((size_t)b << 12);
    const float* g1 = P1 + ((size_t)b << 12);
    float ig = sigm(g0[j] + g1[j] + bias[j]);
    float fg = sigm(g0[1024 + j] + g1[1024 + j] + bias[1024 + j]);
    float gg = tanhf(g0[2048 + j] + g1[2048 + j] + bias[2048 + j]);
    float og = sigm(g0[3072 + j] + g1[3072 + j] + bias[3072 + j]);
    float c = fg * cx[idx] + ig * gg;
    float h = og * tanhf(c);
    oc[idx] = c;
    oh[idx] = h;
    hbf[idx] = f2bf(h);
}

extern "C" void kernel_launch(void* const* d_in, const int* in_sizes, int n_in,
                              void* d_out, int out_size, void* d_ws, size_t ws_size,
                              hipStream_t stream) {
    const float* x        = (const float*)d_in[0];
    const float* hx       = (const float*)d_in[1];
    const float* cx       = (const float*)d_in[2];
    const float* W_ih_dec = (const float*)d_in[3];
    const float* W_hh_dec = (const float*)d_in[4];
    const float* b_ih_dec = (const float*)d_in[5];
    const float* b_hh_dec = (const float*)d_in[6];
    const float* W_r0     = (const float*)d_in[7];
    const float* b_r0     = (const float*)d_in[8];
    const float* W_rp     = (const float*)d_in[9];
    const float* b_rp     = (const float*)d_in[10];
    const float* W_rr     = (const float*)d_in[11];
    const float* b_rr     = (const float*)d_in[12];
    const float* W_s0     = (const float*)d_in[13];
    const float* b_s0     = (const float*)d_in[14];
    const float* W_ih_sta = (const float*)d_in[15];
    const float* W_hh_sta = (const float*)d_in[16];
    const float* b_ih_sta = (const float*)d_in[17];
    const float* b_hh_sta = (const float*)d_in[18];
    const float* W_sn     = (const float*)d_in[19];
    const float* b_sn     = (const float*)d_in[20];
    float* out = (float*)d_out;

    float* Act    = out;                          // [1024][512]
    float* ActBar = out + 524288;                 // [32][1024][512]
    float* Hx2    = out + 524288 + 16777216;      // [1024][1024]
    float* Cx2    = Hx2 + 1048576;                // [1024][1024]

    char* ws = (char*)d_ws;
    size_t off = 0;
    auto alloc = [&](size_t bytes) -> void* {
        void* p = ws + off;
        off += (bytes + 255) & ~(size_t)255;
        return p;
    };
    ushort_t* WcatD = (ushort_t*)alloc(4096ull * 1536 * 2);  // [4096][512|1024]
    ushort_t* Wr0b  = (ushort_t*)alloc(1024ull * 1024 * 2);
    ushort_t* Wrpb  = (ushort_t*)alloc(512ull * 1024 * 2);
    ushort_t* Wrrb  = (ushort_t*)alloc(512ull * 512 * 2);
    ushort_t* Ws0b  = (ushort_t*)alloc(1024ull * 1024 * 2);
    ushort_t* Wsnb  = (ushort_t*)alloc(512ull * 1024 * 2);
    ushort_t* WcatS = (ushort_t*)alloc(4096ull * 3072 * 2);  // [4096][2048|1024]
    float*    biasD = (float*)alloc(4096 * 4);
    float*    biasS = (float*)alloc(4096 * 4);
    float*    gates = (float*)alloc(2ull * 1024 * 4096 * 4); // 2 split-K partials
    ushort_t* Acat  = (ushort_t*)alloc(1024ull * 1536 * 2);  // [r(512) | hd(1024)]
    ushort_t* Acat2 = (ushort_t*)alloc(1024ull * 3072 * 2);  // [x | xbar | hx]
    float*    cd    = (float*)alloc(1024ull * 1024 * 4);
    float*    hsum  = (float*)alloc(1024ull * 1024 * 4);
    ushort_t* pbuf  = (ushort_t*)alloc(1024ull * 512 * 2);
    ushort_t* hbarb = (ushort_t*)alloc(1024ull * 1024 * 2);
    ushort_t* hx2b  = (ushort_t*)alloc(1024ull * 1024 * 2);
    if (ws_size < off) return;  // insufficient workspace -> fail loudly in validation

    const size_t GZ = 1024ull * 4096;  // split-K partial stride (elements)
    float* gatesP1 = gates + GZ;

    // ---- weight packing (runs every call; ~85 MB of traffic) ----
    pack2_bf<<<dim3(6, 4096), 256, 0, stream>>>(WcatD, W_ih_dec, 512, W_hh_dec, 1024);
    pack2_bf<<<dim3(4, 1024), 256, 0, stream>>>(Wr0b, W_r0, 1024, nullptr, 0);
    pack2_bf<<<dim3(4, 512), 256, 0, stream>>>(Wrpb, W_rp, 1024, nullptr, 0);
    pack2_bf<<<dim3(2, 512), 256, 0, stream>>>(Wrrb, W_rr, 512, nullptr, 0);
    pack2_bf<<<dim3(4, 1024), 256, 0, stream>>>(Ws0b, W_s0, 1024, nullptr, 0);
    pack2_bf<<<dim3(4, 512), 256, 0, stream>>>(Wsnb, W_sn, 1024, nullptr, 0);
    pack2_bf<<<dim3(12, 4096), 256, 0, stream>>>(WcatS, W_ih_sta, 2048, W_hh_sta, 1024);
    addvec<<<16, 256, 0, stream>>>(biasD, b_ih_dec, b_hh_dec);
    addvec<<<16, 256, 0, stream>>>(biasS, b_ih_sta, b_hh_sta);
    init_dec<<<4096, 256, 0, stream>>>(cx, cd, hsum, Acat);
    init_sta<<<4096, 256, 0, stream>>>(x, hx, Acat2);

    // hd0 = hx @ W_r0^T + b_r0  -> Acat cols 512..1535 (bf16)
    gemm_bt<false, true, false><<<dim3(8, 8, 1), 256, 0, stream>>>(
        Acat2 + 2048, 3072, Wr0b, 1024, 1024, 0, b_r0,
        nullptr, 0, 0, Acat + 512, 1536);

    // ---- decoder loop ----
    for (int t = 0; t < 32; t++) {
        // gates partials = [r|hd] @ [W_ih|W_hh]^T, split-K=2 (768 each)
        gemm_bt<true, false, false><<<dim3(32, 8, 2), 256, 0, stream>>>(
            Acat, 1536, WcatD, 1536, 768, 768, nullptr,
            gates, 4096, GZ, nullptr, 0);
        lstm_dec_pw<<<4096, 256, 0, stream>>>(gates, gatesP1, biasD, cd, Acat, hsum);
        // p = hd @ W_rp^T + b_rp  -> Act_bar[t] (fp32) and pbuf (bf16)
        gemm_bt<true, true, false><<<dim3(4, 8, 1), 256, 0, stream>>>(
            Acat + 512, 1536, Wrpb, 1024, 1024, 0, b_rp,
            ActBar + (size_t)t * 524288, 512, 0, pbuf, 512);
        // r = p @ W_rr^T + b_rr -> Acat cols 0..511 (skip on last step)
        if (t < 31)
            gemm_bt<false, true, false><<<dim3(4, 8, 1), 256, 0, stream>>>(
                pbuf, 512, Wrrb, 512, 512, 0, b_rr,
                nullptr, 0, 0, Acat, 1536);
    }

    // hbar = mean(fts_bar); xbar = relu(hbar @ W_s0^T + b_s0) -> Acat2 cols 1024..2047
    hbar_bf_k<<<4096, 256, 0, stream>>>(hsum, hbarb);
    gemm_bt<false, true, true><<<dim3(8, 8, 1), 256, 0, stream>>>(
        hbarb, 1024, Ws0b, 1024, 1024, 0, b_s0,
        nullptr, 0, 0, Acat2 + 1024, 3072);

    // static LSTM: gates partials = [x|xbar|hx] @ [W_ih_sta|W_hh_sta]^T, split-K=2
    gemm_bt<true, false, false><<<dim3(32, 8, 2), 256, 0, stream>>>(
        Acat2, 3072, WcatS, 3072, 1536, 1536, nullptr,
        gates, 4096, GZ, nullptr, 0);
    lstm_sta_pw<<<4096, 256, 0, stream>>>(gates, gatesP1, biasS, cx, Hx2, Cx2, hx2b);

    // Act = hx2 @ W_sn^T + b_sn
    gemm_bt<true, false, false><<<dim3(4, 8, 1), 256, 0, stream>>>(
        hx2b, 1024, Wsnb, 1024, 1024, 0, b_sn,
        Act, 512, 0, nullptr, 0);

    (void)in_sizes; (void)n_in; (void)out_size;
}

// Round 4
// 1280.186 us; speedup vs baseline: 2.3906x; 2.2356x over previous
//
#include <hip/hip_runtime.h>
#include <hip/hip_bf16.h>
#include <stdint.h>

// B=1024, D_in=1024, D_hid=1024, D_out=512, D_future=32
// Outputs: Act [1024*512], Act_bar [32*1024*512], hx2 [1024*1024], cx2 [1024*1024]
//
// Algebraic restructure: r_t = hd_t@Wrp2^T + br2  (Wrp2 = Wrr@Wrp), so
//   gates_t = hd_{t-1} @ (W_ih@Wrp2 + W_hh)^T + (biasD + W_ih@br2)   [t>=1]
//   gates_0 = hd0 @ W_hh^T + biasD                                    [r0 = 0]
// Loop = 32 fused GEMM+LSTM launches (K=1024). All p_t batched at the end.

typedef unsigned short ushort_t;
typedef __attribute__((ext_vector_type(8))) short short8;   // 8 x bf16
typedef __attribute__((ext_vector_type(4))) float floatx4;  // 4 x fp32 acc

__device__ __forceinline__ unsigned short f2bf(float f) {
    unsigned int u = __float_as_uint(f);
    u += 0x7FFF + ((u >> 16) & 1);   // RNE
    return (unsigned short)(u >> 16);
}
__device__ __forceinline__ float sigm(float x) { return 1.f / (1.f + __expf(-x)); }

__device__ __forceinline__ void glds16(const ushort_t* g, const ushort_t* l) {
    __builtin_amdgcn_global_load_lds(
        (const __attribute__((address_space(1))) uint32_t*)g,
        (__attribute__((address_space(3))) uint32_t*)l, 16, 0, 0);
}

// ---------------- generic GEMM (round-2 proven, zero LDS conflicts) ----------
// C[m][n] = sum_k A[m][k]*Bw[n][k] (+bias[n]), optional relu; fp32/bf16 out.
// Grid (N/128, M/128, kz), block 256.
template <bool WF, bool WB, bool RELU>
__global__ __launch_bounds__(256)
void gemm_bt(const ushort_t* __restrict__ A, int lda,
             const ushort_t* __restrict__ Bw, int ldb,
             int Kloop, int kzOff,
             const float* __restrict__ bias,
             float* __restrict__ Cf, int ldcf, size_t czStride,
             ushort_t* __restrict__ Cb, int ldcb) {
    __shared__ __align__(16) ushort_t As[128 * 32];
    __shared__ __align__(16) ushort_t Bs[128 * 32];
    const int t = threadIdx.x;
    const int l = t & 63;
    const int w = t >> 6;
    const int m0 = blockIdx.y << 7;
    const int n0 = blockIdx.x << 7;
    const int kz = blockIdx.z;
    A  += (size_t)kz * kzOff;
    Bw += (size_t)kz * kzOff;
    if (WF) Cf += (size_t)kz * czStride;
    const int wm = (w >> 1) << 6;
    const int wn = (w & 1) << 6;
    const int lr = l & 15;
    const int lg = l >> 4;

    floatx4 acc[4][4] = {};

    const int srow = (w << 4) + (l >> 2);
    const int cc = ((l & 3) - ((l >> 3) & 3)) & 3;
    const int scol = cc << 3;
    const ushort_t* Ag0 = A + (size_t)(m0 + srow) * lda + scol;
    const ushort_t* Ag1 = A + (size_t)(m0 + 64 + srow) * lda + scol;
    const ushort_t* Bg0 = Bw + (size_t)(n0 + srow) * ldb + scol;
    const ushort_t* Bg1 = Bw + (size_t)(n0 + 64 + srow) * ldb + scol;
    const ushort_t* lA0 = &As[t * 8];
    const ushort_t* lA1 = &As[2048 + t * 8];
    const ushort_t* lB0 = &Bs[t * 8];
    const ushort_t* lB1 = &Bs[2048 + t * 8];

    int aoff[4], boff[4];
#pragma unroll
    for (int i = 0; i < 4; i++) {
        const int Ra = wm + i * 16 + lr;
        aoff[i] = ((Ra << 2) + ((lg + ((Ra >> 1) & 3)) & 3)) << 3;
        const int Rb = wn + i * 16 + lr;
        boff[i] = ((Rb << 2) + ((lg + ((Rb >> 1) & 3)) & 3)) << 3;
    }

    for (int kk = 0; kk < Kloop; kk += 32) {
        glds16(Ag0 + kk, lA0);
        glds16(Ag1 + kk, lA1);
        glds16(Bg0 + kk, lB0);
        glds16(Bg1 + kk, lB1);
        __syncthreads();
        short8 af[4], bfr[4];
#pragma unroll
        for (int i = 0; i < 4; i++) af[i] = *(const short8*)&As[aoff[i]];
#pragma unroll
        for (int j = 0; j < 4; j++) bfr[j] = *(const short8*)&Bs[boff[j]];
#pragma unroll
        for (int i = 0; i < 4; i++)
#pragma unroll
            for (int j = 0; j < 4; j++)
                acc[i][j] = __builtin_amdgcn_mfma_f32_16x16x32_bf16(af[i], bfr[j], acc[i][j], 0, 0, 0);
        __syncthreads();
    }

#pragma unroll
    for (int i = 0; i < 4; i++) {
#pragma unroll
        for (int j = 0; j < 4; j++) {
            const int col = n0 + wn + j * 16 + lr;
            const float bv = bias ? bias[col] : 0.f;
#pragma unroll
            for (int r = 0; r < 4; r++) {
                const int row = m0 + wm + i * 16 + lg * 4 + r;
                float v = acc[i][j][r] + bv;
                if (RELU) v = fmaxf(v, 0.f);
                if (WF) Cf[(size_t)row * ldcf + col] = v;
                if (WB) Cb[(size_t)row * ldcb + col] = f2bf(v);
            }
        }
    }
}

// ---------------- fused gates GEMM + LSTM pointwise ---------------------------
// A [1024][lda] bf16; WI [4096][K] bf16 with interleaved rows (row 4u+g = gate
// g, unit u); biasI [4096] fp32 interleaved. Tile 64x128, grid (32, 16),
// block 256 (4 waves, each 64 rows x 32 cols). LDS double-buffered staging:
// prefetch issued AFTER the barrier so the compiler's vmcnt(0)-before-barrier
// drains the previous step's loads, not the prefetch.
// Epilogue: acc -> Cs (fp32, padded) -> coalesced readback computes LSTM.
template <bool HSUM, bool HF>
__global__ __launch_bounds__(256)
void gates_fused(const ushort_t* __restrict__ A, int lda,
                 const ushort_t* __restrict__ WI, int K,
                 const float* __restrict__ biasI,
                 const float* __restrict__ cin, float* __restrict__ cout,
                 ushort_t* __restrict__ hbf, int ldh,
                 float* __restrict__ hsum, float* __restrict__ hf) {
    __shared__ __align__(16) ushort_t As[2][64 * 32];
    __shared__ __align__(16) ushort_t Bs[2][128 * 32];
    __shared__ __align__(16) float Cs[64 * 132];   // +4 pad per row: no conflicts
    const int t = threadIdx.x;
    const int l = t & 63;
    const int w = t >> 6;
    const int m0 = blockIdx.y << 6;    // 64-row tile
    const int n0 = blockIdx.x << 7;    // 128 cols = 32 units
    const int u0 = blockIdx.x << 5;
    const int lr = l & 15;
    const int lg = l >> 4;

    floatx4 acc[4][2] = {};

    // staging: thread t stages chunk (row t>>2, swizzled cc) at slot t
    const int srow = t >> 2;
    const int cc = ((t & 3) - ((t >> 3) & 3)) & 3;
    const int scol = cc << 3;
    const ushort_t* Ag  = A  + (size_t)(m0 + srow) * lda + scol;
    const ushort_t* Bg0 = WI + (size_t)(n0 + srow) * K + scol;
    const ushort_t* Bg1 = WI + (size_t)(n0 + 64 + srow) * K + scol;
    const ushort_t* lAp[2]  = { &As[0][t * 8], &As[1][t * 8] };
    const ushort_t* lBp0[2] = { &Bs[0][t * 8], &Bs[1][t * 8] };
    const ushort_t* lBp1[2] = { &Bs[0][2048 + t * 8], &Bs[1][2048 + t * 8] };

    // fragment offsets: chunk (R, lg) at slot 4R + ((lg + (R>>1)) & 3)
    int aoff[4], boff[2];
#pragma unroll
    for (int i = 0; i < 4; i++) {
        const int Ra = i * 16 + lr;
        aoff[i] = ((Ra << 2) + ((lg + ((Ra >> 1) & 3)) & 3)) << 3;
    }
#pragma unroll
    for (int jf = 0; jf < 2; jf++) {
        const int Rb = (w << 5) + jf * 16 + lr;
        boff[jf] = ((Rb << 2) + ((lg + ((Rb >> 1) & 3)) & 3)) << 3;
    }

    auto issue = [&](int b, int kk) {
        glds16(Ag + kk, lAp[b]);
        glds16(Bg0 + kk, lBp0[b]);
        glds16(Bg1 + kk, lBp1[b]);
    };
    auto compute = [&](int b) {
        short8 af[4], bfr[2];
#pragma unroll
        for (int i = 0; i < 4; i++) af[i] = *(const short8*)&As[b][aoff[i]];
#pragma unroll
        for (int jf = 0; jf < 2; jf++) bfr[jf] = *(const short8*)&Bs[b][boff[jf]];
#pragma unroll
        for (int i = 0; i < 4; i++)
#pragma unroll
            for (int jf = 0; jf < 2; jf++)
                acc[i][jf] = __builtin_amdgcn_mfma_f32_16x16x32_bf16(af[i], bfr[jf], acc[i][jf], 0, 0, 0);
    };

    issue(0, 0);
    for (int kk = 0; kk < K; kk += 64) {
        __syncthreads();              // drains buf0 loads; buf1 prefetch not yet issued
        issue(1, kk + 32);            // in flight during compute(0)
        compute(0);
        __syncthreads();              // drains buf1 loads
        if (kk + 64 < K) issue(0, kk + 64);
        compute(1);
    }

    // ---- epilogue: acc -> Cs ----
#pragma unroll
    for (int i = 0; i < 4; i++)
#pragma unroll
        for (int jf = 0; jf < 2; jf++) {
            const int colb = (w << 5) + jf * 16 + lr;
#pragma unroll
            for (int r = 0; r < 4; r++)
                Cs[(i * 16 + lg * 4 + r) * 132 + colb] = acc[i][jf][r];
        }
    __syncthreads();

    // readback: 8 passes, 64 (row,unit) pairs each; coalesced along units
#pragma unroll
    for (int p = 0; p < 8; p++) {
        const int row = p * 8 + (t >> 5);
        const int uu = t & 31;
        const float4 g4 = *(const float4*)&Cs[row * 132 + uu * 4];
        const int grow = m0 + row;
        const int gu = u0 + uu;
        const float4 b4 = *(const float4*)&biasI[gu * 4];
        const float iv = sigm(g4.x + b4.x);
        const float fv = sigm(g4.y + b4.y);
        const float gv = tanhf(g4.z + b4.z);
        const float ov = sigm(g4.w + b4.w);
        const size_t cidx = (size_t)grow * 1024 + gu;
        const float c = fv * cin[cidx] + iv * gv;
        const float h = ov * tanhf(c);
        cout[cidx] = c;
        hbf[(size_t)grow * ldh + gu] = f2bf(h);
        if (HSUM) hsum[cidx] += h;
        if (HF) hf[cidx] = h;
    }
}

// ---------------- small prep kernels -----------------------------------------
__global__ void pack2_bf(ushort_t* __restrict__ dst, const float* __restrict__ s1, int K1,
                         const float* __restrict__ s2, int K2) {
    const int n = blockIdx.y;
    const int k = blockIdx.x * 256 + threadIdx.x;
    const int Kt = K1 + K2;
    float v = (k < K1) ? s1[(size_t)n * K1 + k] : s2[(size_t)n * K2 + (k - K1)];
    dst[(size_t)n * Kt + k] = f2bf(v);
}

// dst[c][r] = bf(src[r][c]); grid (R/256, C)
__global__ void tpose_bf(ushort_t* __restrict__ dst, const float* __restrict__ src,
                         int R, int C) {
    const int c = blockIdx.y;
    const int r = blockIdx.x * 256 + threadIdx.x;
    dst[(size_t)c * R + r] = f2bf(src[(size_t)r * C + c]);
}

// WhhI[4u+g][k] = bf(Whh[(g<<10)+u][k]); grid (4, 4096)
__global__ void ileave_whh_k(ushort_t* __restrict__ dst, const float* __restrict__ Whh) {
    const int rI = blockIdx.y;
    const int k = blockIdx.x * 256 + threadIdx.x;
    const int r = ((rI & 3) << 10) + (rI >> 2);
    dst[(size_t)rI * 1024 + k] = f2bf(Whh[(size_t)r * 1024 + k]);
}

// WgI[4u+g][k] = bf(Wgf[r][k] + Whh[r][k]); grid (4, 4096)
__global__ void ileave_add_k(ushort_t* __restrict__ dst, const float* __restrict__ Wgf,
                             const float* __restrict__ Whh) {
    const int rI = blockIdx.y;
    const int k = blockIdx.x * 256 + threadIdx.x;
    const int r = ((rI & 3) << 10) + (rI >> 2);
    dst[(size_t)rI * 1024 + k] = f2bf(Wgf[(size_t)r * 1024 + k] + Whh[(size_t)r * 1024 + k]);
}

// WcatSI[4u+g][k]: k<2048 from Wih_sta[r][k], else Whh_sta[r][k-2048]; grid (12, 4096)
__global__ void ileave_sta_k(ushort_t* __restrict__ dst, const float* __restrict__ Wih,
                             const float* __restrict__ Whh) {
    const int rI = blockIdx.y;
    const int k = blockIdx.x * 256 + threadIdx.x;
    const int r = ((rI & 3) << 10) + (rI >> 2);
    float v = (k < 2048) ? Wih[(size_t)r * 2048 + k] : Whh[(size_t)r * 1024 + (k - 2048)];
    dst[(size_t)rI * 3072 + k] = f2bf(v);
}

// biasI[4u+g] = b_ih[r] + b_hh[r]; grid 16
__global__ void bias_il_k(float* __restrict__ dst, const float* __restrict__ b_ih,
                          const float* __restrict__ b_hh) {
    const int rI = blockIdx.x * 256 + threadIdx.x;
    const int r = ((rI & 3) << 10) + (rI >> 2);
    dst[rI] = b_ih[r] + b_hh[r];
}

// br2[o] = b_rr[o] + Wrr[o]·b_rp ; grid 2
__global__ void br2_k(float* __restrict__ br2, const float* __restrict__ Wrr,
                      const float* __restrict__ b_rp, const float* __restrict__ b_rr) {
    const int o = blockIdx.x * 256 + threadIdx.x;
    float s = b_rr[o];
    for (int m = 0; m < 512; m++) s += Wrr[o * 512 + m] * b_rp[m];
    br2[o] = s;
}

// biasGI[4u+g] = b_ih[r]+b_hh[r] + W_ih[r]·br2 ; grid 16
__global__ void biasg_k(float* __restrict__ dst, const float* __restrict__ Wih,
                        const float* __restrict__ b_ih, const float* __restrict__ b_hh,
                        const float* __restrict__ br2) {
    const int rI = blockIdx.x * 256 + threadIdx.x;
    const int r = ((rI & 3) << 10) + (rI >> 2);
    float s = b_ih[r] + b_hh[r];
    for (int o = 0; o < 512; o++) s += Wih[(size_t)r * 512 + o] * br2[o];
    dst[rI] = s;
}

__global__ void init_dec(const float* __restrict__ cx, float* __restrict__ cd,
                         float* __restrict__ hsum) {
    int idx = blockIdx.x * 256 + threadIdx.x;
    cd[idx] = cx[idx];
    hsum[idx] = 0.f;
}

// Acat2: cols 0..1023 = bf(x), cols 2048..3071 = bf(hx)
__global__ void init_sta(const float* __restrict__ x, const float* __restrict__ hx,
                         ushort_t* __restrict__ A2) {
    int idx = blockIdx.x * 256 + threadIdx.x;
    int b = idx >> 10, j = idx & 1023;
    A2[(size_t)b * 3072 + j] = f2bf(x[idx]);
    A2[(size_t)b * 3072 + 2048 + j] = f2bf(hx[idx]);
}

__global__ void hbar_bf_k(const float* __restrict__ hsum, ushort_t* __restrict__ out) {
    int idx = blockIdx.x * 256 + threadIdx.x;
    out[idx] = f2bf(hsum[idx] * (1.f / 32.f));
}

extern "C" void kernel_launch(void* const* d_in, const int* in_sizes, int n_in,
                              void* d_out, int out_size, void* d_ws, size_t ws_size,
                              hipStream_t stream) {
    const float* x        = (const float*)d_in[0];
    const float* hx       = (const float*)d_in[1];
    const float* cx       = (const float*)d_in[2];
    const float* W_ih_dec = (const float*)d_in[3];
    const float* W_hh_dec = (const float*)d_in[4];
    const float* b_ih_dec = (const float*)d_in[5];
    const float* b_hh_dec = (const float*)d_in[6];
    const float* W_r0     = (const float*)d_in[7];
    const float* b_r0     = (const float*)d_in[8];
    const float* W_rp     = (const float*)d_in[9];
    const float* b_rp     = (const float*)d_in[10];
    const float* W_rr     = (const float*)d_in[11];
    const float* b_rr     = (const float*)d_in[12];
    const float* W_s0     = (const float*)d_in[13];
    const float* b_s0     = (const float*)d_in[14];
    const float* W_ih_sta = (const float*)d_in[15];
    const float* W_hh_sta = (const float*)d_in[16];
    const float* b_ih_sta = (const float*)d_in[17];
    const float* b_hh_sta = (const float*)d_in[18];
    const float* W_sn     = (const float*)d_in[19];
    const float* b_sn     = (const float*)d_in[20];
    float* out = (float*)d_out;

    float* Act    = out;                          // [1024][512]
    float* ActBar = out + 524288;                 // [32][1024][512]
    float* Hx2    = out + 524288 + 16777216;      // [1024][1024]
    float* Cx2    = Hx2 + 1048576;                // [1024][1024]

    char* ws = (char*)d_ws;
    size_t off = 0;
    auto alloc = [&](size_t bytes) -> void* {
        void* p = ws + off;
        off += (bytes + 255) & ~(size_t)255;
        return p;
    };
    const size_t SLOT = 1048576;  // one [1024][1024] bf16 slab (elements)
    ushort_t* HDall  = (ushort_t*)alloc(33ull * SLOT * 2);   // hd0 + 32 hd's (69 MB)
    ushort_t* WgI    = (ushort_t*)alloc(4096ull * 1024 * 2); // folded loop weight
    ushort_t* WcatSI = (ushort_t*)alloc(4096ull * 3072 * 2); // static interleaved
    ushort_t* Wrpb   = (ushort_t*)alloc(512ull * 1024 * 2);
    ushort_t* Wr0b   = (ushort_t*)alloc(1024ull * 1024 * 2);
    ushort_t* Ws0b   = (ushort_t*)alloc(1024ull * 1024 * 2);
    ushort_t* Wsnb   = (ushort_t*)alloc(512ull * 1024 * 2);
    float*    biasDI = (float*)alloc(4096 * 4);
    float*    biasGI = (float*)alloc(4096 * 4);
    float*    biasSI = (float*)alloc(4096 * 4);
    float*    br2    = (float*)alloc(512 * 4);
    ushort_t* Acat2  = (ushort_t*)alloc(1024ull * 3072 * 2); // [x | xbar | hx]
    float*    cd     = (float*)alloc(1024ull * 1024 * 4);
    float*    hsum   = (float*)alloc(1024ull * 1024 * 4);
    ushort_t* hbarb  = (ushort_t*)alloc(1024ull * 1024 * 2);
    ushort_t* hx2b   = (ushort_t*)alloc(1024ull * 1024 * 2);
    if (ws_size < off) return;

    // Prep scratch aliased into HDall slots 1..16 — each consumed before the
    // decoder loop overwrites its slot (slot s+1 first written at step s).
    float*    Wgf    = (float*)(HDall + 1 * SLOT);    // slots 1-8 (16 MB fp32)
    ushort_t* Wihb   = HDall + 9 * SLOT;              // slots 9-10
    ushort_t* WrpT   = HDall + 11 * SLOT;             // 1 MB
    ushort_t* Wrp2Tb = HDall + 11 * SLOT + 524288;    // 1 MB
    ushort_t* Wrrb   = HDall + 12 * SLOT;             // 0.5 MB
    ushort_t* WhhI   = HDall + 13 * SLOT;             // slots 13-16 (8 MB), read at s=0 only

    // ---- packing & weight folding ----
    init_dec<<<4096, 256, 0, stream>>>(cx, cd, hsum);
    init_sta<<<4096, 256, 0, stream>>>(x, hx, Acat2);
    pack2_bf<<<dim3(2, 512), 256, 0, stream>>>(Wrrb, W_rr, 512, nullptr, 0);
    pack2_bf<<<dim3(2, 4096), 256, 0, stream>>>(Wihb, W_ih_dec, 512, nullptr, 0);
    pack2_bf<<<dim3(4, 512), 256, 0, stream>>>(Wrpb, W_rp, 1024, nullptr, 0);
    pack2_bf<<<dim3(4, 1024), 256, 0, stream>>>(Wr0b, W_r0, 1024, nullptr, 0);
    pack2_bf<<<dim3(4, 1024), 256, 0, stream>>>(Ws0b, W_s0, 1024, nullptr, 0);
    pack2_bf<<<dim3(4, 512), 256, 0, stream>>>(Wsnb, W_sn, 1024, nullptr, 0);
    tpose_bf<<<dim3(2, 1024), 256, 0, stream>>>(WrpT, W_rp, 512, 1024);
    ileave_whh_k<<<dim3(4, 4096), 256, 0, stream>>>(WhhI, W_hh_dec);
    bias_il_k<<<16, 256, 0, stream>>>(biasDI, b_ih_dec, b_hh_dec);
    ileave_sta_k<<<dim3(12, 4096), 256, 0, stream>>>(WcatSI, W_ih_sta, W_hh_sta);
    bias_il_k<<<16, 256, 0, stream>>>(biasSI, b_ih_sta, b_hh_sta);
    br2_k<<<2, 256, 0, stream>>>(br2, W_rr, b_rp, b_rr);
    biasg_k<<<16, 256, 0, stream>>>(biasGI, W_ih_dec, b_ih_dec, b_hh_dec, br2);

    // Wrp2T[k][o] = sum_m Wrp[m][k]*Wrr[o][m]  (M=1024,N=512,K=512)
    gemm_bt<false, true, false><<<dim3(4, 8, 1), 256, 0, stream>>>(
        WrpT, 512, Wrrb, 512, 512, 0, nullptr, nullptr, 0, 0, Wrp2Tb, 512);
    // Wgf[r][k] = sum_o W_ih[r][o]*Wrp2[o][k]  (M=4096,N=1024,K=512) fp32
    gemm_bt<true, false, false><<<dim3(8, 32, 1), 256, 0, stream>>>(
        Wihb, 512, Wrp2Tb, 512, 512, 0, nullptr, Wgf, 1024, 0, nullptr, 0);
    // WgI = interleave(Wgf + W_hh)
    ileave_add_k<<<dim3(4, 4096), 256, 0, stream>>>(WgI, Wgf, W_hh_dec);

    // hd0 = hx @ W_r0^T + b_r0 -> HDall slot 0 (bf16)
    gemm_bt<false, true, false><<<dim3(8, 8, 1), 256, 0, stream>>>(
        Acat2 + 2048, 3072, Wr0b, 1024, 1024, 0, b_r0, nullptr, 0, 0, HDall, 1024);

    // ---- decoder loop: 32 fused GEMM+LSTM launches ----
    for (int s = 0; s < 32; s++) {
        const ushort_t* WI = (s == 0) ? WhhI : WgI;
        const float* bI = (s == 0) ? biasDI : biasGI;
        gates_fused<true, false><<<dim3(32, 16), 256, 0, stream>>>(
            HDall + (size_t)s * SLOT, 1024, WI, 1024, bI,
            cd, cd, HDall + (size_t)(s + 1) * SLOT, 1024, hsum, nullptr);
    }

    // ---- batched p: ActBar[s] = hd_{s+1} @ Wrp^T + b_rp  (M=32768,N=512,K=1024)
    gemm_bt<true, false, false><<<dim3(4, 256, 1), 256, 0, stream>>>(
        HDall + SLOT, 1024, Wrpb, 1024, 1024, 0, b_rp, ActBar, 512, 0, nullptr, 0);

    // hbar; xbar = relu(hbar @ W_s0^T + b_s0) -> Acat2 cols 1024..2047
    hbar_bf_k<<<4096, 256, 0, stream>>>(hsum, hbarb);
    gemm_bt<false, true, true><<<dim3(8, 8, 1), 256, 0, stream>>>(
        hbarb, 1024, Ws0b, 1024, 1024, 0, b_s0, nullptr, 0, 0, Acat2 + 1024, 3072);

    // static LSTM fused (K=3072): -> Hx2 (fp32), Cx2 (fp32), hx2b (bf16)
    gates_fused<false, true><<<dim3(32, 16), 256, 0, stream>>>(
        Acat2, 3072, WcatSI, 3072, biasSI, cx, Cx2, hx2b, 1024, nullptr, Hx2);

    // Act = hx2 @ W_sn^T + b_sn
    gemm_bt<true, false, false><<<dim3(4, 8, 1), 256, 0, stream>>>(
        hx2b, 1024, Wsnb, 1024, 1024, 0, b_sn, Act, 512, 0, nullptr, 0);

    (void)in_sizes; (void)n_in; (void)out_size;
}

// Round 5
// 1234.034 us; speedup vs baseline: 2.4800x; 1.0374x over previous
//
#include <hip/hip_runtime.h>
#include <hip/hip_bf16.h>
#include <stdint.h>

// B=1024, D_in=1024, D_hid=1024, D_out=512, D_future=32
// Outputs: Act [1024*512], Act_bar [32*1024*512], hx2 [1024*1024], cx2 [1024*1024]
//
// Algebraic restructure: r_t = hd_t@Wrp2^T + br2  (Wrp2 = Wrr@Wrp), so
//   gates_t = hd_{t-1} @ (W_ih@Wrp2 + W_hh)^T + (biasD + W_ih@br2)   [t>=1]
//   gates_0 = hd0 @ W_hh^T + biasD                                    [r0 = 0]
// Loop = 32 fused GEMM+LSTM launches (K=1024). All p_t batched at the end.
// hbar computed at the end from the 32 stored bf16 hd slots.

typedef unsigned short ushort_t;
typedef __attribute__((ext_vector_type(8))) short short8;   // 8 x bf16
typedef __attribute__((ext_vector_type(4))) float floatx4;  // 4 x fp32 acc

__device__ __forceinline__ unsigned short f2bf(float f) {
    unsigned int u = __float_as_uint(f);
    u += 0x7FFF + ((u >> 16) & 1);   // RNE
    return (unsigned short)(u >> 16);
}
__device__ __forceinline__ float bf2f(unsigned short u) {
    return __uint_as_float(((unsigned int)u) << 16);
}
__device__ __forceinline__ float sigm(float x) { return 1.f / (1.f + __expf(-x)); }

__device__ __forceinline__ void glds16(const ushort_t* g, const ushort_t* l) {
    __builtin_amdgcn_global_load_lds(
        (const __attribute__((address_space(1))) uint32_t*)g,
        (__attribute__((address_space(3))) uint32_t*)l, 16, 0, 0);
}

// ---------------- generic GEMM (round-2 proven, zero LDS conflicts) ----------
// C[m][n] = sum_k A[m][k]*Bw[n][k] (+bias[n]), optional relu; fp32/bf16 out.
// NT: nontemporal fp32 stores (pure outputs, avoid RFO). Grid (N/128, M/128, kz).
template <bool WF, bool WB, bool RELU, bool NT>
__global__ __launch_bounds__(256)
void gemm_bt(const ushort_t* __restrict__ A, int lda,
             const ushort_t* __restrict__ Bw, int ldb,
             int Kloop, int kzOff,
             const float* __restrict__ bias,
             float* __restrict__ Cf, int ldcf, size_t czStride,
             ushort_t* __restrict__ Cb, int ldcb) {
    __shared__ __align__(16) ushort_t As[128 * 32];
    __shared__ __align__(16) ushort_t Bs[128 * 32];
    const int t = threadIdx.x;
    const int l = t & 63;
    const int w = t >> 6;
    const int m0 = blockIdx.y << 7;
    const int n0 = blockIdx.x << 7;
    const int kz = blockIdx.z;
    A  += (size_t)kz * kzOff;
    Bw += (size_t)kz * kzOff;
    if (WF) Cf += (size_t)kz * czStride;
    const int wm = (w >> 1) << 6;
    const int wn = (w & 1) << 6;
    const int lr = l & 15;
    const int lg = l >> 4;

    floatx4 acc[4][4] = {};

    const int srow = (w << 4) + (l >> 2);
    const int cc = ((l & 3) - ((l >> 3) & 3)) & 3;
    const int scol = cc << 3;
    const ushort_t* Ag0 = A + (size_t)(m0 + srow) * lda + scol;
    const ushort_t* Ag1 = A + (size_t)(m0 + 64 + srow) * lda + scol;
    const ushort_t* Bg0 = Bw + (size_t)(n0 + srow) * ldb + scol;
    const ushort_t* Bg1 = Bw + (size_t)(n0 + 64 + srow) * ldb + scol;
    const ushort_t* lA0 = &As[t * 8];
    const ushort_t* lA1 = &As[2048 + t * 8];
    const ushort_t* lB0 = &Bs[t * 8];
    const ushort_t* lB1 = &Bs[2048 + t * 8];

    int aoff[4], boff[4];
#pragma unroll
    for (int i = 0; i < 4; i++) {
        const int Ra = wm + i * 16 + lr;
        aoff[i] = ((Ra << 2) + ((lg + ((Ra >> 1) & 3)) & 3)) << 3;
        const int Rb = wn + i * 16 + lr;
        boff[i] = ((Rb << 2) + ((lg + ((Rb >> 1) & 3)) & 3)) << 3;
    }

    for (int kk = 0; kk < Kloop; kk += 32) {
        glds16(Ag0 + kk, lA0);
        glds16(Ag1 + kk, lA1);
        glds16(Bg0 + kk, lB0);
        glds16(Bg1 + kk, lB1);
        __syncthreads();
        short8 af[4], bfr[4];
#pragma unroll
        for (int i = 0; i < 4; i++) af[i] = *(const short8*)&As[aoff[i]];
#pragma unroll
        for (int j = 0; j < 4; j++) bfr[j] = *(const short8*)&Bs[boff[j]];
#pragma unroll
        for (int i = 0; i < 4; i++)
#pragma unroll
            for (int j = 0; j < 4; j++)
                acc[i][j] = __builtin_amdgcn_mfma_f32_16x16x32_bf16(af[i], bfr[j], acc[i][j], 0, 0, 0);
        __syncthreads();
    }

#pragma unroll
    for (int i = 0; i < 4; i++) {
#pragma unroll
        for (int j = 0; j < 4; j++) {
            const int col = n0 + wn + j * 16 + lr;
            const float bv = bias ? bias[col] : 0.f;
#pragma unroll
            for (int r = 0; r < 4; r++) {
                const int row = m0 + wm + i * 16 + lg * 4 + r;
                float v = acc[i][j][r] + bv;
                if (RELU) v = fmaxf(v, 0.f);
                if (WF) {
                    if (NT) __builtin_nontemporal_store(v, &Cf[(size_t)row * ldcf + col]);
                    else Cf[(size_t)row * ldcf + col] = v;
                }
                if (WB) Cb[(size_t)row * ldcb + col] = f2bf(v);
            }
        }
    }
}

// ---------------- fused gates GEMM + LSTM pointwise ---------------------------
// A [1024][lda] bf16; WI [4096][K] bf16, interleaved rows (4u+g); biasI fp32.
// Tile 64x128, grid (32,16), block 256. K-loop: A staged in LDS in 128-k spans
// (double-buffered, 4x glds16 per span; barrier every 128k instead of 32k).
// B (weights) are per-wave -> straight to a 2-span register ring, no LDS.
// Cs epilogue buffer ALIASES the A buffers (barrier-separated).
template <bool HF, bool NT>
__global__ __launch_bounds__(256, 2)
void gates_fused(const ushort_t* __restrict__ A, int lda,
                 const ushort_t* __restrict__ WI, int K,
                 const float* __restrict__ biasI,
                 const float* __restrict__ cin, float* __restrict__ cout,
                 ushort_t* __restrict__ hbf, int ldh,
                 float* __restrict__ hf) {
    __shared__ __align__(16) float Cs[64 * 132];         // 33.8 KB
    ushort_t* AsBase = (ushort_t*)Cs;                    // 2 bufs x 8192 elems = 32 KB
    const int t = threadIdx.x;
    const int l = t & 63;
    const int w = t >> 6;
    const int m0 = blockIdx.y << 6;    // 64-row tile
    const int n0 = blockIdx.x << 7;    // 128 gate-rows = 32 units
    const int u0 = blockIdx.x << 5;
    const int lr = l & 15;
    const int lg = l >> 4;

    floatx4 acc[4][2] = {};

    // A staging: thread t stages chunk (row t>>2, swizzled cc); per span,
    // sub-tile s (32-k) lives at AsBase[buf*8192 + s*2048 + t*8].
    const int srow = t >> 2;
    const int cc = ((t & 3) - ((t >> 3) & 3)) & 3;
    const int scol = cc << 3;
    const ushort_t* Ag = A + (size_t)(m0 + srow) * lda + scol;

    // A fragment offsets within a 2048-elem sub-tile
    int aoff[4];
#pragma unroll
    for (int i = 0; i < 4; i++) {
        const int Ra = i * 16 + lr;
        aoff[i] = ((Ra << 2) + ((lg + ((Ra >> 1) & 3)) & 3)) << 3;
    }
    // B: per-wave direct global loads
    const ushort_t* BgW[2];
#pragma unroll
    for (int jf = 0; jf < 2; jf++)
        BgW[jf] = WI + (size_t)(n0 + (w << 5) + jf * 16 + lr) * K + (lg << 3);

    auto issueA = [&](int b, int sp) {
#pragma unroll
        for (int s = 0; s < 4; s++)
            glds16(Ag + sp * 128 + s * 32, AsBase + b * 8192 + s * 2048 + t * 8);
    };
    auto loadB = [&](short8 (&br)[4][2], int sp) {
#pragma unroll
        for (int s = 0; s < 4; s++)
#pragma unroll
            for (int jf = 0; jf < 2; jf++)
                br[s][jf] = *(const short8*)(BgW[jf] + sp * 128 + s * 32);
    };
    auto compute = [&](int b, short8 (&br)[4][2]) {
#pragma unroll
        for (int s = 0; s < 4; s++) {
            short8 af[4];
#pragma unroll
            for (int i = 0; i < 4; i++)
                af[i] = *(const short8*)(AsBase + b * 8192 + s * 2048 + aoff[i]);
#pragma unroll
            for (int i = 0; i < 4; i++)
#pragma unroll
                for (int jf = 0; jf < 2; jf++)
                    acc[i][jf] = __builtin_amdgcn_mfma_f32_16x16x32_bf16(af[i], br[s][jf], acc[i][jf], 0, 0, 0);
        }
    };

    short8 b0[4][2], b1[4][2];
    const int NS = K >> 7;            // 128-k spans (8 or 24; always even)
    issueA(0, 0);
    loadB(b0, 0);
    for (int sp = 0; sp < NS; sp += 2) {
        __syncthreads();              // drains span sp loads (in flight one span)
        if (sp + 1 < NS) { issueA(1, sp + 1); loadB(b1, sp + 1); }
        compute(0, b0);
        __syncthreads();              // drains span sp+1 loads
        if (sp + 2 < NS) { issueA(0, sp + 2); loadB(b0, sp + 2); }
        compute(1, b1);
    }
    __syncthreads();                  // all ds_reads done before Cs overwrites As

    // ---- epilogue: acc -> Cs (padded, conflict-free) ----
#pragma unroll
    for (int i = 0; i < 4; i++)
#pragma unroll
        for (int jf = 0; jf < 2; jf++) {
            const int colb = (w << 5) + jf * 16 + lr;
#pragma unroll
            for (int r = 0; r < 4; r++)
                Cs[(i * 16 + lg * 4 + r) * 132 + colb] = acc[i][jf][r];
        }
    __syncthreads();

    // readback: coalesced along units; LSTM pointwise
#pragma unroll
    for (int p = 0; p < 8; p++) {
        const int row = p * 8 + (t >> 5);
        const int uu = t & 31;
        const float4 g4 = *(const float4*)&Cs[row * 132 + uu * 4];
        const int grow = m0 + row;
        const int gu = u0 + uu;
        const float4 b4 = *(const float4*)&biasI[gu * 4];
        const float iv = sigm(g4.x + b4.x);
        const float fv = sigm(g4.y + b4.y);
        const float gv = tanhf(g4.z + b4.z);
        const float ov = sigm(g4.w + b4.w);
        const size_t cidx = (size_t)grow * 1024 + gu;
        const float c = fv * cin[cidx] + iv * gv;
        const float h = ov * tanhf(c);
        if (NT) __builtin_nontemporal_store(c, &cout[cidx]);
        else cout[cidx] = c;
        hbf[(size_t)grow * ldh + gu] = f2bf(h);
        if (HF) {
            if (NT) __builtin_nontemporal_store(h, &hf[cidx]);
            else hf[cidx] = h;
        }
    }
}

// ---------------- small prep kernels -----------------------------------------
__global__ void pack2_bf(ushort_t* __restrict__ dst, const float* __restrict__ s1, int K1,
                         const float* __restrict__ s2, int K2) {
    const int n = blockIdx.y;
    const int k = blockIdx.x * 256 + threadIdx.x;
    const int Kt = K1 + K2;
    float v = (k < K1) ? s1[(size_t)n * K1 + k] : s2[(size_t)n * K2 + (k - K1)];
    dst[(size_t)n * Kt + k] = f2bf(v);
}

// dst[c][r] = bf(src[r][c]); grid (R/256, C)
__global__ void tpose_bf(ushort_t* __restrict__ dst, const float* __restrict__ src,
                         int R, int C) {
    const int c = blockIdx.y;
    const int r = blockIdx.x * 256 + threadIdx.x;
    dst[(size_t)c * R + r] = f2bf(src[(size_t)r * C + c]);
}

// WhhI[4u+g][k] = bf(Whh[(g<<10)+u][k]); grid (4, 4096)
__global__ void ileave_whh_k(ushort_t* __restrict__ dst, const float* __restrict__ Whh) {
    const int rI = blockIdx.y;
    const int k = blockIdx.x * 256 + threadIdx.x;
    const int r = ((rI & 3) << 10) + (rI >> 2);
    dst[(size_t)rI * 1024 + k] = f2bf(Whh[(size_t)r * 1024 + k]);
}

// WgI[4u+g][k] = bf(Wgf[r][k] + Whh[r][k]); grid (4, 4096)
__global__ void ileave_add_k(ushort_t* __restrict__ dst, const float* __restrict__ Wgf,
                             const float* __restrict__ Whh) {
    const int rI = blockIdx.y;
    const int k = blockIdx.x * 256 + threadIdx.x;
    const int r = ((rI & 3) << 10) + (rI >> 2);
    dst[(size_t)rI * 1024 + k] = f2bf(Wgf[(size_t)r * 1024 + k] + Whh[(size_t)r * 1024 + k]);
}

// WcatSI[4u+g][k]: k<2048 from Wih_sta[r][k], else Whh_sta[r][k-2048]; grid (12, 4096)
__global__ void ileave_sta_k(ushort_t* __restrict__ dst, const float* __restrict__ Wih,
                             const float* __restrict__ Whh) {
    const int rI = blockIdx.y;
    const int k = blockIdx.x * 256 + threadIdx.x;
    const int r = ((rI & 3) << 10) + (rI >> 2);
    float v = (k < 2048) ? Wih[(size_t)r * 2048 + k] : Whh[(size_t)r * 1024 + (k - 2048)];
    dst[(size_t)rI * 3072 + k] = f2bf(v);
}

// biasI[4u+g] = b_ih[r] + b_hh[r]; grid 16
__global__ void bias_il_k(float* __restrict__ dst, const float* __restrict__ b_ih,
                          const float* __restrict__ b_hh) {
    const int rI = blockIdx.x * 256 + threadIdx.x;
    const int r = ((rI & 3) << 10) + (rI >> 2);
    dst[rI] = b_ih[r] + b_hh[r];
}

// br2[o] = b_rr[o] + Wrr[o]·b_rp ; grid 2
__global__ void br2_k(float* __restrict__ br2, const float* __restrict__ Wrr,
                      const float* __restrict__ b_rp, const float* __restrict__ b_rr) {
    const int o = blockIdx.x * 256 + threadIdx.x;
    float s = b_rr[o];
    for (int m = 0; m < 512; m++) s += Wrr[o * 512 + m] * b_rp[m];
    br2[o] = s;
}

// biasGI[4u+g] = b_ih[r]+b_hh[r] + W_ih[r]·br2 ; grid 16
__global__ void biasg_k(float* __restrict__ dst, const float* __restrict__ Wih,
                        const float* __restrict__ b_ih, const float* __restrict__ b_hh,
                        const float* __restrict__ br2) {
    const int rI = blockIdx.x * 256 + threadIdx.x;
    const int r = ((rI & 3) << 10) + (rI >> 2);
    float s = b_ih[r] + b_hh[r];
    for (int o = 0; o < 512; o++) s += Wih[(size_t)r * 512 + o] * br2[o];
    dst[rI] = s;
}

__global__ void init_dec(const float* __restrict__ cx, float* __restrict__ cd) {
    int idx = blockIdx.x * 256 + threadIdx.x;
    cd[idx] = cx[idx];
}

// Acat2: cols 0..1023 = bf(x), cols 2048..3071 = bf(hx)
__global__ void init_sta(const float* __restrict__ x, const float* __restrict__ hx,
                         ushort_t* __restrict__ A2) {
    int idx = blockIdx.x * 256 + threadIdx.x;
    int b = idx >> 10, j = idx & 1023;
    A2[(size_t)b * 3072 + j] = f2bf(x[idx]);
    A2[(size_t)b * 3072 + 2048 + j] = f2bf(hx[idx]);
}

// hbar bf16 from 32 bf16 hd slots: out = bf(mean_s HD1[s*SLOT + idx])
__global__ void hbar_from_slots(const ushort_t* __restrict__ HD1,
                                ushort_t* __restrict__ out) {
    const size_t SLOT = 1048576;
    int idx = blockIdx.x * 256 + threadIdx.x;
    float s = 0.f;
#pragma unroll 8
    for (int t = 0; t < 32; t++) s += bf2f(HD1[(size_t)t * SLOT + idx]);
    out[idx] = f2bf(s * (1.f / 32.f));
}

extern "C" void kernel_launch(void* const* d_in, const int* in_sizes, int n_in,
                              void* d_out, int out_size, void* d_ws, size_t ws_size,
                              hipStream_t stream) {
    const float* x        = (const float*)d_in[0];
    const float* hx       = (const float*)d_in[1];
    const float* cx       = (const float*)d_in[2];
    const float* W_ih_dec = (const float*)d_in[3];
    const float* W_hh_dec = (const float*)d_in[4];
    const float* b_ih_dec = (const float*)d_in[5];
    const float* b_hh_dec = (const float*)d_in[6];
    const float* W_r0     = (const float*)d_in[7];
    const float* b_r0     = (const float*)d_in[8];
    const float* W_rp     = (const float*)d_in[9];
    const float* b_rp     = (const float*)d_in[10];
    const float* W_rr     = (const float*)d_in[11];
    const float* b_rr     = (const float*)d_in[12];
    const float* W_s0     = (const float*)d_in[13];
    const float* b_s0     = (const float*)d_in[14];
    const float* W_ih_sta = (const float*)d_in[15];
    const float* W_hh_sta = (const float*)d_in[16];
    const float* b_ih_sta = (const float*)d_in[17];
    const float* b_hh_sta = (const float*)d_in[18];
    const float* W_sn     = (const float*)d_in[19];
    const float* b_sn     = (const float*)d_in[20];
    float* out = (float*)d_out;

    float* Act    = out;                          // [1024][512]
    float* ActBar = out + 524288;                 // [32][1024][512]
    float* Hx2    = out + 524288 + 16777216;      // [1024][1024]
    float* Cx2    = Hx2 + 1048576;                // [1024][1024]

    char* ws = (char*)d_ws;
    size_t off = 0;
    auto alloc = [&](size_t bytes) -> void* {
        void* p = ws + off;
        off += (bytes + 255) & ~(size_t)255;
        return p;
    };
    const size_t SLOT = 1048576;  // one [1024][1024] bf16 slab (elements)
    ushort_t* HDall  = (ushort_t*)alloc(33ull * SLOT * 2);   // hd0 + 32 hd's (69 MB)
    ushort_t* WgI    = (ushort_t*)alloc(4096ull * 1024 * 2); // folded loop weight
    ushort_t* WcatSI = (ushort_t*)alloc(4096ull * 3072 * 2); // static interleaved
    ushort_t* Wrpb   = (ushort_t*)alloc(512ull * 1024 * 2);
    ushort_t* Wr0b   = (ushort_t*)alloc(1024ull * 1024 * 2);
    ushort_t* Ws0b   = (ushort_t*)alloc(1024ull * 1024 * 2);
    ushort_t* Wsnb   = (ushort_t*)alloc(512ull * 1024 * 2);
    float*    biasDI = (float*)alloc(4096 * 4);
    float*    biasGI = (float*)alloc(4096 * 4);
    float*    biasSI = (float*)alloc(4096 * 4);
    float*    br2    = (float*)alloc(512 * 4);
    ushort_t* Acat2  = (ushort_t*)alloc(1024ull * 3072 * 2); // [x | xbar | hx]
    float*    cd     = (float*)alloc(1024ull * 1024 * 4);
    ushort_t* hbarb  = (ushort_t*)alloc(1024ull * 1024 * 2);
    ushort_t* hx2b   = (ushort_t*)alloc(1024ull * 1024 * 2);
    if (ws_size < off) return;

    // Prep scratch aliased into HDall slots 1..16 — each consumed before the
    // decoder loop overwrites its slot (slot s+1 first written at step s).
    float*    Wgf    = (float*)(HDall + 1 * SLOT);    // slots 1-8 (16 MB fp32)
    ushort_t* Wihb   = HDall + 9 * SLOT;              // slots 9-10
    ushort_t* WrpT   = HDall + 11 * SLOT;             // 1 MB
    ushort_t* Wrp2Tb = HDall + 11 * SLOT + 524288;    // 1 MB
    ushort_t* Wrrb   = HDall + 12 * SLOT;             // 0.5 MB
    ushort_t* WhhI   = HDall + 13 * SLOT;             // slots 13-16, read at s=0 only

    // ---- packing & weight folding ----
    init_dec<<<4096, 256, 0, stream>>>(cx, cd);
    init_sta<<<4096, 256, 0, stream>>>(x, hx, Acat2);
    pack2_bf<<<dim3(2, 512), 256, 0, stream>>>(Wrrb, W_rr, 512, nullptr, 0);
    pack2_bf<<<dim3(2, 4096), 256, 0, stream>>>(Wihb, W_ih_dec, 512, nullptr, 0);
    pack2_bf<<<dim3(4, 512), 256, 0, stream>>>(Wrpb, W_rp, 1024, nullptr, 0);
    pack2_bf<<<dim3(4, 1024), 256, 0, stream>>>(Wr0b, W_r0, 1024, nullptr, 0);
    pack2_bf<<<dim3(4, 1024), 256, 0, stream>>>(Ws0b, W_s0, 1024, nullptr, 0);
    pack2_bf<<<dim3(4, 512), 256, 0, stream>>>(Wsnb, W_sn, 1024, nullptr, 0);
    tpose_bf<<<dim3(2, 1024), 256, 0, stream>>>(WrpT, W_rp, 512, 1024);
    ileave_whh_k<<<dim3(4, 4096), 256, 0, stream>>>(WhhI, W_hh_dec);
    bias_il_k<<<16, 256, 0, stream>>>(biasDI, b_ih_dec, b_hh_dec);
    ileave_sta_k<<<dim3(12, 4096), 256, 0, stream>>>(WcatSI, W_ih_sta, W_hh_sta);
    bias_il_k<<<16, 256, 0, stream>>>(biasSI, b_ih_sta, b_hh_sta);
    br2_k<<<2, 256, 0, stream>>>(br2, W_rr, b_rp, b_rr);
    biasg_k<<<16, 256, 0, stream>>>(biasGI, W_ih_dec, b_ih_dec, b_hh_dec, br2);

    // Wrp2T[k][o] = sum_m Wrp[m][k]*Wrr[o][m]  (M=1024,N=512,K=512)
    gemm_bt<false, true, false, false><<<dim3(4, 8, 1), 256, 0, stream>>>(
        WrpT, 512, Wrrb, 512, 512, 0, nullptr, nullptr, 0, 0, Wrp2Tb, 512);
    // Wgf[r][k] = sum_o W_ih[r][o]*Wrp2[o][k]  (M=4096,N=1024,K=512) fp32
    gemm_bt<true, false, false, false><<<dim3(8, 32, 1), 256, 0, stream>>>(
        Wihb, 512, Wrp2Tb, 512, 512, 0, nullptr, Wgf, 1024, 0, nullptr, 0);
    // WgI = interleave(Wgf + W_hh)
    ileave_add_k<<<dim3(4, 4096), 256, 0, stream>>>(WgI, Wgf, W_hh_dec);

    // hd0 = hx @ W_r0^T + b_r0 -> HDall slot 0 (bf16)
    gemm_bt<false, true, false, false><<<dim3(8, 8, 1), 256, 0, stream>>>(
        Acat2 + 2048, 3072, Wr0b, 1024, 1024, 0, b_r0, nullptr, 0, 0, HDall, 1024);

    // ---- decoder loop: 32 fused GEMM+LSTM launches ----
    for (int s = 0; s < 32; s++) {
        const ushort_t* WI = (s == 0) ? WhhI : WgI;
        const float* bI = (s == 0) ? biasDI : biasGI;
        gates_fused<false, false><<<dim3(32, 16), 256, 0, stream>>>(
            HDall + (size_t)s * SLOT, 1024, WI, 1024, bI,
            cd, cd, HDall + (size_t)(s + 1) * SLOT, 1024, nullptr);
    }

    // ---- batched p: ActBar[s] = hd_{s+1} @ Wrp^T + b_rp  (M=32768,N=512,K=1024)
    gemm_bt<true, false, false, true><<<dim3(4, 256, 1), 256, 0, stream>>>(
        HDall + SLOT, 1024, Wrpb, 1024, 1024, 0, b_rp, ActBar, 512, 0, nullptr, 0);

    // hbar from hd slots; xbar = relu(hbar @ W_s0^T + b_s0) -> Acat2 cols 1024..2047
    hbar_from_slots<<<4096, 256, 0, stream>>>(HDall + SLOT, hbarb);
    gemm_bt<false, true, true, false><<<dim3(8, 8, 1), 256, 0, stream>>>(
        hbarb, 1024, Ws0b, 1024, 1024, 0, b_s0, nullptr, 0, 0, Acat2 + 1024, 3072);

    // static LSTM fused (K=3072): -> Hx2 (fp32), Cx2 (fp32), hx2b (bf16)
    gates_fused<true, true><<<dim3(32, 16), 256, 0, stream>>>(
        Acat2, 3072, WcatSI, 3072, biasSI, cx, Cx2, hx2b, 1024, Hx2);

    // Act = hx2 @ W_sn^T + b_sn
    gemm_bt<true, false, false, true><<<dim3(4, 8, 1), 256, 0, stream>>>(
        hx2b, 1024, Wsnb, 1024, 1024, 0, b_sn, Act, 512, 0, nullptr, 0);

    (void)in_sizes; (void)n_in; (void)out_size;
}